// Round 4
// baseline (6011.303 us; speedup 1.0000x reference)
//
#include <hip/hip_runtime.h>
#include <cstdint>
#include <cstddef>

#define NNODE 118
#define TSEQ  2048
#define TC    512          // chunk length (TSEQ/4)
#define NCH   4
#define BSTEP 32           // steps staged per LDS batch
#define NEGC  -1000000000.0f

typedef __fp16 h2v __attribute__((ext_vector_type(2)));
typedef short short8 __attribute__((ext_vector_type(8)));
typedef float floatx4 __attribute__((ext_vector_type(4)));

__device__ __forceinline__ float leakyf(float x){ return x >= 0.f ? x : 0.01f * x; }
__device__ __forceinline__ float sigm(float x){ return 1.f / (1.f + __expf(-x)); }
__device__ __forceinline__ float tanhfast(float x){ float e = __expf(2.f * x); return 1.f - 2.f / (e + 1.f); }

__device__ __forceinline__ unsigned short bf16rne(float x){
  unsigned int u = __builtin_bit_cast(unsigned int, x);
  u = (u + 0x7fffu + ((u >> 16) & 1u)) >> 16;
  return (unsigned short)u;
}

__device__ __forceinline__ float fdot2(h2v a, h2v b, float c){
#if __has_builtin(__builtin_amdgcn_fdot2)
  return __builtin_amdgcn_fdot2(a, b, c, false);
#else
  return c + (float)a.x * (float)b.x + (float)a.y * (float)b.y;
#endif
}
__device__ __forceinline__ h2v bch2(unsigned int u){ return __builtin_bit_cast(h2v, u); }

__device__ float bred_sum(float v, float* buf, int nthr){
  int tid = threadIdx.x;
  buf[tid] = v; __syncthreads();
  for (int s = nthr >> 1; s > 0; s >>= 1){
    if (tid < s) buf[tid] += buf[tid + s];
    __syncthreads();
  }
  float r = buf[0]; __syncthreads(); return r;
}
__device__ float bred_max(float v, float* buf, int nthr){
  int tid = threadIdx.x;
  buf[tid] = v; __syncthreads();
  for (int s = nthr >> 1; s > 0; s >>= 1){
    if (tid < s) buf[tid] = fmaxf(buf[tid], buf[tid + s]);
    __syncthreads();
  }
  float r = buf[0]; __syncthreads(); return r;
}

// ---------------- converts ----------------
__global__ void f32_to_bf16_k(const float* __restrict__ in, unsigned short* __restrict__ out, int n){
  int i = blockIdx.x * blockDim.x + threadIdx.x;
  if (i < n) out[i] = bf16rne(in[i]);
}
__global__ void f32_to_f16_k(const float* __restrict__ in, __fp16* __restrict__ out, int n){
  int i = blockIdx.x * blockDim.x + threadIdx.x;
  if (i < n) out[i] = (__fp16)in[i];
}

// ---------------- pre-gate GEMM: pre[m, g] = sum_k A[m,k] * W[g,k] (bf16 MFMA) ----------------
__global__ __launch_bounds__(256, 4) void pregemm(
    const void* __restrict__ Aptr, int a_f32,
    const unsigned short* __restrict__ Wb,   // bf16 [512][128]
    __fp16* __restrict__ pre,                // [NNODE*TC][512]
    int t0)
{
  const int tid = threadIdx.x, lane = tid & 63, wv = tid >> 6;
  const int blk = blockIdx.x;
  const int n = blk / (TC / 64), tb = blk % (TC / 64);
  const int rbase_pre = n * TC + tb * 64 + wv * 16;
  const size_t rbase_gl = (size_t)n * TSEQ + t0 + tb * 64 + wv * 16;
  const int r16 = lane & 15, kq = lane >> 4;
  __shared__ __fp16 lds[4][16 * 132];

  short8 af[4];
  if (a_f32){
    const float* A = (const float*)Aptr;
    #pragma unroll
    for (int kt = 0; kt < 4; kt++){
      const float* p = A + (rbase_gl + r16) * 128 + kt * 32 + kq * 8;
      float4 x0 = ((const float4*)p)[0];
      float4 x1 = ((const float4*)p)[1];
      short8 s;
      s[0] = (short)bf16rne(x0.x); s[1] = (short)bf16rne(x0.y);
      s[2] = (short)bf16rne(x0.z); s[3] = (short)bf16rne(x0.w);
      s[4] = (short)bf16rne(x1.x); s[5] = (short)bf16rne(x1.y);
      s[6] = (short)bf16rne(x1.z); s[7] = (short)bf16rne(x1.w);
      af[kt] = s;
    }
  } else {
    const unsigned short* A = (const unsigned short*)Aptr;
    #pragma unroll
    for (int kt = 0; kt < 4; kt++){
      const unsigned short* p = A + (rbase_gl + r16) * 128 + kt * 32 + kq * 8;
      af[kt] = __builtin_bit_cast(short8, *(const uint4*)p);
    }
  }

  __fp16* lw = &lds[wv][0];
  for (int g8 = 0; g8 < 4; g8++){
    #pragma unroll
    for (int ntc = 0; ntc < 8; ntc++){
      int nt = g8 * 8 + ntc;
      floatx4 acc = {0.f, 0.f, 0.f, 0.f};
      #pragma unroll
      for (int kt = 0; kt < 4; kt++){
        const unsigned short* bp = Wb + (size_t)(nt * 16 + r16) * 128 + kt * 32 + kq * 8;
        short8 bfr = __builtin_bit_cast(short8, *(const uint4*)bp);
        acc = __builtin_amdgcn_mfma_f32_16x16x32_bf16(af[kt], bfr, acc, 0, 0, 0);
      }
      #pragma unroll
      for (int r = 0; r < 4; r++){
        int crow = kq * 4 + r, ccol = ntc * 16 + r16;
        lw[crow * 132 + ccol] = (__fp16)acc[r];
      }
    }
    #pragma unroll
    for (int i = 0; i < 4; i++){
      int r2 = i * 4 + kq, ch = r16;
      uint4 v = *(const uint4*)&lw[r2 * 132 + ch * 8];
      *(uint4*)(pre + ((size_t)(rbase_pre + r2)) * 512 + g8 * 128 + ch * 8) = v;
    }
  }
}

// ---------------- LSTM scan v4 ----------------
// 512 threads, 1 gate/thread, weights in 64 h2v VGPRs. One barrier per step.
// Step loop NOT unrolled (keeps RA happy -- v3's unrolled body spilled to scratch).
// Pre-gates staged 32 steps (32KB LDS) per batch; hout captured in 4 named regs/wave.
__global__ __launch_bounds__(512, 2) void lstm_scan_v4(
    const __fp16* __restrict__ pre,      // [NNODE][TC][512]
    const __fp16* __restrict__ Whh16,    // [512][128] fp16
    const float* __restrict__ b_ih,
    const float* __restrict__ b_hh,
    unsigned int* __restrict__ hout,     // bf16-pairs [NNODE][TSEQ][64] or null
    float* __restrict__ pout,            // [NNODE][128] or null (last chunk L2)
    unsigned int* __restrict__ h_state,  // fp16-pairs [NNODE][64]
    float* __restrict__ c_state,         // [NNODE][128]
    int t0)
{
  const int n = blockIdx.x, tid = threadIdx.x;
  const int w = tid >> 6, lane = tid & 63;
  __shared__ unsigned int lds_h[8][64];     // per-wave private h copies (fp16 pairs)
  __shared__ float lds_g[2][512];           // ping-pong gate buffer
  __shared__ __fp16 lds_pre[BSTEP * 512];   // staged pre-gates for BSTEP steps (32KB)

  h2v wh[64];
  {
    const uint4* wrow = (const uint4*)(Whh16 + (size_t)tid * 128);
    #pragma unroll
    for (int kk = 0; kk < 16; kk++){
      uint4 v = wrow[kk];
      wh[4 * kk + 0] = bch2(v.x); wh[4 * kk + 1] = bch2(v.y);
      wh[4 * kk + 2] = bch2(v.z); wh[4 * kk + 3] = bch2(v.w);
    }
  }
  const float biasg = b_ih[tid] + b_hh[tid];

  float2 c; unsigned int hcur;
  if (t0 == 0){ c.x = 0.f; c.y = 0.f; hcur = 0u; }
  else { c = ((const float2*)c_state)[n * 64 + lane]; hcur = h_state[n * 64 + lane]; }
  lds_h[w][lane] = hcur;
  float hl0 = 0.f, hl1 = 0.f;

  const __fp16* pchunk = pre + (size_t)n * TC * 512;
  unsigned int* hrow = hout ? hout + (size_t)n * TSEQ * 64 : nullptr;

  #pragma unroll 1
  for (int bt = 0; bt < TC / BSTEP; bt++){
    // stage BSTEP steps of pre-gates (32KB, coalesced, 4 uint4/thread)
    {
      const uint4* src = (const uint4*)(pchunk + (size_t)bt * BSTEP * 512);
      uint4* dst = (uint4*)lds_pre;
      #pragma unroll
      for (int i = 0; i < BSTEP / 8; i++) dst[i * 512 + tid] = src[i * 512 + tid];
    }
    __syncthreads();                       // B0: staging visible (drains vmem once per 32 steps)

    unsigned int hA = 0, hB = 0, hC = 0, hD = 0;
    #pragma unroll 1
    for (int s = 0; s < BSTEP; s++){
      const int buf = s & 1;
      // ---- phase 1: gate GEMV (reads own wave's h copy; weights in VGPRs) ----
      float acc0 = (float)lds_pre[s * 512 + tid] + biasg;
      float acc1 = 0.f, acc2 = 0.f, acc3 = 0.f;
      const uint4* h4 = (const uint4*)(&lds_h[w][0]);
      #pragma unroll
      for (int k = 0; k < 16; k++){
        uint4 hv = h4[k];
        acc0 = fdot2(wh[4 * k + 0], bch2(hv.x), acc0);
        acc1 = fdot2(wh[4 * k + 1], bch2(hv.y), acc1);
        acc2 = fdot2(wh[4 * k + 2], bch2(hv.z), acc2);
        acc3 = fdot2(wh[4 * k + 3], bch2(hv.w), acc3);
      }
      lds_g[buf][tid] = (acc0 + acc1) + (acc2 + acc3);
      __syncthreads();                     // B1: the only per-step barrier (lgkm-only)

      // ---- phase 2 (redundant per wave): update own 2 elems ----
      float2 gi = *(const float2*)&lds_g[buf][2 * lane];
      float2 gf = *(const float2*)&lds_g[buf][128 + 2 * lane];
      float2 gg = *(const float2*)&lds_g[buf][256 + 2 * lane];
      float2 go = *(const float2*)&lds_g[buf][384 + 2 * lane];
      c.x = sigm(gf.x) * c.x + sigm(gi.x) * tanhfast(gg.x);
      c.y = sigm(gf.y) * c.y + sigm(gi.y) * tanhfast(gg.y);
      float h0 = sigm(go.x) * tanhfast(c.x);
      float h1 = sigm(go.y) * tanhfast(c.y);
      h2v hp; hp.x = (__fp16)h0; hp.y = (__fp16)h1;
      hcur = __builtin_bit_cast(unsigned int, hp);
      lds_h[w][lane] = hcur;
      unsigned int hb = (unsigned int)bf16rne(h0) | ((unsigned int)bf16rne(h1) << 16);
      if      (s == w)      hA = hb;
      else if (s == w + 8)  hB = hb;
      else if (s == w + 16) hC = hb;
      else if (s == w + 24) hD = hb;
      hl0 = h0; hl1 = h1;
    }
    // wave w stores rows w, w+8, w+16, w+24 of this batch (drains at next B0)
    if (hrow){
      size_t rb = (size_t)(t0 + bt * BSTEP);
      hrow[(rb + w)      * 64 + lane] = hA;
      hrow[(rb + w + 8)  * 64 + lane] = hB;
      hrow[(rb + w + 16) * 64 + lane] = hC;
      hrow[(rb + w + 24) * 64 + lane] = hD;
    }
  }

  if (w == 0){
    h_state[n * 64 + lane] = hcur;
    ((float2*)c_state)[n * 64 + lane] = c;
    if (pout){
      float2 pv; pv.x = leakyf(hl0); pv.y = leakyf(hl1);
      ((float2*)pout)[n * 64 + lane] = pv;
    }
  }
}

// ---------------- H1: per-node MLP up to n ----------------
__global__ void node_mlp(
    const float* __restrict__ x_tag, const float* __restrict__ pm,
    const float* __restrict__ Wvm, const float* __restrict__ Wup,
    const float* __restrict__ W_hyb, const float* __restrict__ b_hyb,
    const float* __restrict__ W_act, const float* __restrict__ b_act,
    const float* __restrict__ W_inact, const float* __restrict__ b_inact,
    const float* __restrict__ p, float* __restrict__ nmat)
{
  int n = blockIdx.x, tid = threadIdx.x;
  __shared__ float pl[128], up[128], vm[128], hh[256];
  float act = x_tag[n * 3 + 2], hp0 = x_tag[n * 3 + 0], hp1 = x_tag[n * 3 + 1];
  if (tid < 128) pl[tid] = p[n * 128 + tid];
  __syncthreads();
  if (tid < 128){
    float a1 = 0.f;
    for (int k = 0; k < 768; k++) a1 += pm[k] * Wvm[k * 128 + tid];
    a1 += act * Wvm[768 * 128 + tid];
    vm[tid] = leakyf(a1);
    float a2 = 0.f;
    for (int k = 0; k < 128; k++) a2 += pl[k] * Wup[k * 128 + tid];
    up[tid] = leakyf(a2);
  }
  __syncthreads();
  {
    float a = b_hyb[tid];
    for (int k = 0; k < 128; k++) a += up[k] * W_hyb[k * 256 + tid];
    for (int k = 0; k < 128; k++) a += (up[k] + vm[k]) * W_hyb[(128 + k) * 256 + tid];
    for (int k = 0; k < 128; k++) a += vm[k] * W_hyb[(256 + k) * 256 + tid];
    hh[tid] = leakyf(a);
  }
  __syncthreads();
  {
    float na = b_act[tid];
    for (int k = 0; k < 256; k++) na += hh[k] * W_act[k * 256 + tid];
    na += hp0 * W_act[256 * 256 + tid] + hp1 * W_act[257 * 256 + tid];
    float ni = b_inact[tid];
    for (int k = 0; k < 256; k++) ni += hh[k] * W_inact[k * 256 + tid];
    nmat[n * 256 + tid] = leakyf(na * (1.f - act) + ni * act);
  }
}

// ---------------- H2: per-node projections of n ----------------
__global__ void node_proj(
    const float* __restrict__ nmat,
    const float* __restrict__ Wphin, const float* __restrict__ Won,
    const float* __restrict__ Weo,
    float* __restrict__ A, float* __restrict__ B,
    float* __restrict__ C, float* __restrict__ D,
    float* __restrict__ Q, float* __restrict__ R)
{
  int n = blockIdx.x, tid = threadIdx.x;
  __shared__ float nl[256];
  nl[tid] = nmat[n * 256 + tid];
  __syncthreads();
  if (tid < 192){
    float a = 0.f, b = 0.f;
    for (int k = 0; k < 256; k++){ float v = nl[k]; a += v * Wphin[k * 192 + tid]; b += v * Wphin[(256 + k) * 192 + tid]; }
    A[n * 192 + tid] = a; B[n * 192 + tid] = b;
  }
  float c = 0.f, d = 0.f, q = 0.f, r = 0.f;
  for (int k = 0; k < 256; k++){
    float v = nl[k];
    c += v * Won[k * 256 + tid];
    d += v * Won[(256 + k) * 256 + tid];
    q += v * Weo[(256 + k) * 256 + tid];
    r += v * Weo[(512 + k) * 256 + tid];
  }
  C[n * 256 + tid] = c; D[n * 256 + tid] = d;
  Q[n * 256 + tid] = q; R[n * 256 + tid] = r;
}

// ---------------- H3: phi ----------------
__global__ void phi_kernel(const float* __restrict__ A, const float* __restrict__ B,
                           const float* __restrict__ aphi, float* __restrict__ phiT)
{
  int j = blockIdx.x, tid = threadIdx.x;
  __shared__ float Aj[192], ap[192];
  for (int k = tid; k < 192; k += 128){ Aj[k] = A[j * 192 + k]; ap[k] = aphi[k]; }
  __syncthreads();
  if (tid < NNODE){
    const float* Bi = B + (size_t)tid * 192;
    float s = 0.f;
    for (int k = 0; k < 192; k++) s += leakyf(Aj[k] + Bi[k]) * ap[k];
    phiT[j * NNODE + tid] = s;
  }
}

// ---------------- H4: masked softmaxes ----------------
__global__ void alpha_kernel(const float* __restrict__ phiT, const float* __restrict__ x_tag,
                             float* __restrict__ alpha)
{
  int j = blockIdx.x, tid = threadIdx.x;
  __shared__ float buf[128];
  bool valid = tid < NNODE;
  float ph = valid ? phiT[j * NNODE + tid] : 0.f;
  float a  = valid ? x_tag[tid * 3 + 2] : -1.f;
  bool v1 = (a == 0.f), v0 = (a == 1.f);

  float c1 = bred_sum((valid && v1) ? 1.f : 0.f, buf, 128);

  float x1 = (valid && v1) ? ph : NEGC;
  float m1 = bred_max(valid ? x1 : -3.4e38f, buf, 128);
  float e1 = valid ? __expf(x1 - m1) : 0.f;
  float s1 = bred_sum(e1, buf, 128);
  float p1 = e1 / s1;

  float x0 = (valid && v0) ? ph : NEGC;
  float m0 = bred_max(valid ? x0 : -3.4e38f, buf, 128);
  float e0 = valid ? __expf(x0 - m0) : 0.f;
  float s0 = bred_sum(e0, buf, 128);
  float p0 = e0 / s0;

  float ma = bred_max(valid ? ph : -3.4e38f, buf, 128);
  float ea = valid ? __expf(ph - ma) : 0.f;
  float sa = bred_sum(ea, buf, 128);
  float pa = ea / sa;

  float pmask = v1 ? p1 : (v0 ? p0 : ph);
  float al = (c1 > 0.f) ? pmask : pa;
  if (valid) alpha[tid * NNODE + j] = al;
}

// ---------------- H5: alpha-weighted sums ----------------
__global__ void att_sum(const float* __restrict__ alpha, const float* __restrict__ C,
                        const float* __restrict__ D, const float* __restrict__ Q,
                        const float* __restrict__ R, const float* __restrict__ nmat,
                        float* __restrict__ T1, float* __restrict__ Spart,
                        float* __restrict__ nrm)
{
  int i = blockIdx.x, tid = threadIdx.x;
  __shared__ float al[128];
  __shared__ float rb[256];
  if (tid < 128) al[tid] = (tid < NNODE) ? alpha[i * NNODE + tid] : 0.f;
  __syncthreads();
  float Di = D[i * 256 + tid];
  float acc1 = 0.f, acc2 = 0.f, sa = 0.f;
  for (int jj = 0; jj < NNODE; jj++){
    float av = al[jj]; sa += av;
    acc1 += av * leakyf(C[jj * 256 + tid] + Di);
    acc2 += av * Q[jj * 256 + tid];
  }
  T1[i * 256 + tid] = acc1;
  Spart[i * 256 + tid] = acc2 + sa * R[i * 256 + tid];
  float nv = nmat[i * 256 + tid];
  float ss = bred_sum(nv * nv, rb, 256);
  if (tid == 0) nrm[i] = fmaxf(sqrtf(ss), 1e-8f);
}

// ---------------- H6: per-node finalize ----------------
__global__ void finalize_node(const float* __restrict__ T1, const float* __restrict__ Spart,
                              const float* __restrict__ Weo, const float* __restrict__ nmat,
                              const float* __restrict__ x_tag, const float* __restrict__ Wi,
                              const float* __restrict__ bi, const float* __restrict__ nrm,
                              float* __restrict__ vvec, float* __restrict__ out)
{
  int i = blockIdx.x, tid = threadIdx.x;
  __shared__ float t1[256];
  __shared__ float rb[256];
  t1[tid] = T1[i * 256 + tid];
  __syncthreads();
  float s = Spart[i * 256 + tid];
  for (int k = 0; k < 256; k++) s += t1[k] * Weo[k * 256 + tid];
  float act = x_tag[i * 3 + 2], hp0 = x_tag[i * 3 + 0], hp1 = x_tag[i * 3 + 1];
  float hm0 = leakyf(act * s);
  float hm1 = leakyf((1.f - act) * s);
  float nd = nmat[i * 256 + tid];
  const float* Wir = Wi + (size_t)i * 1536;
  float y0 = nd * Wir[tid * 2]     + hm0 * Wir[(256 + tid) * 2]     + hm1 * Wir[(512 + tid) * 2];
  float y1 = nd * Wir[tid * 2 + 1] + hm0 * Wir[(256 + tid) * 2 + 1] + hm1 * Wir[(512 + tid) * 2 + 1];
  y0 = bred_sum(y0, rb, 256);
  y1 = bred_sum(y1, rb, 256);
  float sgn = (hp1 > hp0) ? 1.f : ((hp1 < hp0) ? -1.f : 0.f);
  if (act == 0.f && sgn != 0.f) atomicAdd(vvec + tid, sgn * nd / nrm[i]);
  if (tid == 0){
    y0 += bi[i * 2]; y1 += bi[i * 2 + 1];
    float m = fmaxf(y0, y1);
    float ee0 = __expf(y0 - m), ee1 = __expf(y1 - m);
    float ssum = ee0 + ee1;
    out[i * 2]     = ee0 / ssum;
    out[i * 2 + 1] = ee1 / ssum;
    out[236 + i * 2]     = hp0;
    out[236 + i * 2 + 1] = hp1;
    out[474 + i] = (act == 0.f) ? 1.f : 0.f;
    out[592 + i] = (act == 1.f) ? 1.f : 0.f;
  }
}

// ---------------- H_ort ----------------
__global__ void ort_kernel(const float* __restrict__ Wum, const float* __restrict__ Wvm,
                           const float* __restrict__ Wup, const float* __restrict__ Wvp,
                           float* __restrict__ misc)
{
  int a = blockIdx.x, b = threadIdx.x;
  float g1 = 0.f, g2 = 0.f, g3 = 0.f, g4 = 0.f;
  for (int r = 0; r < 769; r++){
    g1 += Wum[r * 128 + a] * Wum[r * 128 + b];
    g2 += Wvm[r * 128 + a] * Wvm[r * 128 + b];
  }
  for (int r = 0; r < 128; r++){
    g3 += Wup[r * 128 + a] * Wup[r * 128 + b];
    g4 += Wvp[r * 128 + a] * Wvp[r * 128 + b];
  }
  __shared__ float rb[128];
  float s1 = bred_sum(g1 * g2, rb, 128);
  float s2 = bred_sum(g3 * g4, rb, 128);
  if (b == 0){ atomicAdd(misc + 0, s1); atomicAdd(misc + 1, s2); }
}

// ---------------- H7: scalars ----------------
__global__ void finalize_scalars(const float* __restrict__ misc, const float* __restrict__ vvec,
                                 float* __restrict__ out)
{
  __shared__ float rb[256];
  int tid = threadIdx.x;
  float v = vvec[tid];
  float ss = bred_sum(v * v, rb, 256);
  if (tid == 0){
    out[472] = sqrtf(misc[0]) + sqrtf(misc[1]);
    out[473] = ss;
  }
}

extern "C" void kernel_launch(void* const* d_in, const int* in_sizes, int n_in,
                              void* d_out, int out_size, void* d_ws, size_t ws_size,
                              hipStream_t stream)
{
  const float* x        = (const float*)d_in[0];
  const float* x_tag    = (const float*)d_in[1];
  const float* W_ih0    = (const float*)d_in[2];
  const float* W_hh0    = (const float*)d_in[3];
  const float* b_ih0    = (const float*)d_in[4];
  const float* b_hh0    = (const float*)d_in[5];
  const float* W_ih1    = (const float*)d_in[6];
  const float* W_hh1    = (const float*)d_in[7];
  const float* b_ih1    = (const float*)d_in[8];
  const float* b_hh1    = (const float*)d_in[9];
  const float* pm       = (const float*)d_in[10];
  const float* Wum      = (const float*)d_in[11];
  const float* Wvm      = (const float*)d_in[12];
  const float* Wup      = (const float*)d_in[13];
  const float* Wvp      = (const float*)d_in[14];
  const float* W_hyb    = (const float*)d_in[15];
  const float* b_hyb    = (const float*)d_in[16];
  const float* W_act    = (const float*)d_in[17];
  const float* b_act    = (const float*)d_in[18];
  const float* W_inact  = (const float*)d_in[19];
  const float* b_inact  = (const float*)d_in[20];
  const float* Wphin    = (const float*)d_in[21];
  const float* aphi     = (const float*)d_in[22];
  const float* Won      = (const float*)d_in[23];
  const float* Weo      = (const float*)d_in[24];
  const float* Wi       = (const float*)d_in[25];
  const float* bi       = (const float*)d_in[26];
  float* out = (float*)d_out;

  char* base = (char*)d_ws;
  size_t off = 0;
  auto take = [&](size_t bytes) -> char* {
    char* p = base + off;
    off += (bytes + 255) & ~(size_t)255;
    return p;
  };
  __fp16* pre          = (__fp16*)take((size_t)NNODE * TC * 512 * 2);           // ~62MB
  unsigned int* h1bf   = (unsigned int*)take((size_t)NNODE * TSEQ * 64 * 4);    // ~59MB (bf16 pairs)
  unsigned short* wf0  = (unsigned short*)take((size_t)512 * 128 * 2);
  unsigned short* wf1  = (unsigned short*)take((size_t)512 * 128 * 2);
  __fp16* wh0h         = (__fp16*)take((size_t)512 * 128 * 2);
  __fp16* wh1h         = (__fp16*)take((size_t)512 * 128 * 2);
  unsigned int* hstate = (unsigned int*)take((size_t)NNODE * 64 * 4);
  float* cstate        = (float*)take((size_t)NNODE * 128 * 4);
  float* pbuf  = (float*)take((size_t)NNODE * 128 * 4);
  float* nmat  = (float*)take((size_t)NNODE * 256 * 4);
  float* Amat  = (float*)take((size_t)NNODE * 192 * 4);
  float* Bmat  = (float*)take((size_t)NNODE * 192 * 4);
  float* Cmat  = (float*)take((size_t)NNODE * 256 * 4);
  float* Dmat  = (float*)take((size_t)NNODE * 256 * 4);
  float* Qmat  = (float*)take((size_t)NNODE * 256 * 4);
  float* Rmat  = (float*)take((size_t)NNODE * 256 * 4);
  float* phiT  = (float*)take((size_t)NNODE * NNODE * 4);
  float* alpha = (float*)take((size_t)NNODE * NNODE * 4);
  float* T1    = (float*)take((size_t)NNODE * 256 * 4);
  float* Spart = (float*)take((size_t)NNODE * 256 * 4);
  float* nrm   = (float*)take((size_t)NNODE * 4);
  float* vvec  = (float*)take(256 * 4);
  float* misc  = (float*)take(8 * 4);

  hipMemsetAsync(vvec, 0, 1024 + 32, stream);

  f32_to_bf16_k<<<256, 256, 0, stream>>>(W_ih0, wf0, 512 * 128);
  f32_to_bf16_k<<<256, 256, 0, stream>>>(W_ih1, wf1, 512 * 128);
  f32_to_f16_k<<<256, 256, 0, stream>>>(W_hh0, wh0h, 512 * 128);
  f32_to_f16_k<<<256, 256, 0, stream>>>(W_hh1, wh1h, 512 * 128);

  const int gemm_grid = NNODE * (TC / 64);
  // Layer 1
  for (int c = 0; c < NCH; c++){
    pregemm<<<gemm_grid, 256, 0, stream>>>((const void*)x, 1, wf0, pre, c * TC);
    lstm_scan_v4<<<NNODE, 512, 0, stream>>>(pre, wh0h, b_ih0, b_hh0,
                                            h1bf, nullptr, hstate, cstate, c * TC);
  }
  // Layer 2
  for (int c = 0; c < NCH; c++){
    pregemm<<<gemm_grid, 256, 0, stream>>>((const void*)h1bf, 0, wf1, pre, c * TC);
    lstm_scan_v4<<<NNODE, 512, 0, stream>>>(pre, wh1h, b_ih1, b_hh1,
                                            nullptr, (c == NCH - 1) ? pbuf : nullptr,
                                            hstate, cstate, c * TC);
  }

  node_mlp<<<NNODE, 256, 0, stream>>>(x_tag, pm, Wvm, Wup, W_hyb, b_hyb,
                                      W_act, b_act, W_inact, b_inact, pbuf, nmat);
  node_proj<<<NNODE, 256, 0, stream>>>(nmat, Wphin, Won, Weo, Amat, Bmat, Cmat, Dmat, Qmat, Rmat);
  phi_kernel<<<NNODE, 128, 0, stream>>>(Amat, Bmat, aphi, phiT);
  alpha_kernel<<<NNODE, 128, 0, stream>>>(phiT, x_tag, alpha);
  att_sum<<<NNODE, 256, 0, stream>>>(alpha, Cmat, Dmat, Qmat, Rmat, nmat, T1, Spart, nrm);
  finalize_node<<<NNODE, 256, 0, stream>>>(T1, Spart, Weo, nmat, x_tag, Wi, bi, nrm, vvec, out);
  ort_kernel<<<128, 128, 0, stream>>>(Wum, Wvm, Wup, Wvp, misc);
  finalize_scalars<<<1, 256, 0, stream>>>(misc, vvec, out);
}

// Round 5
// 3795.155 us; speedup vs baseline: 1.5839x; 1.5839x over previous
//
#include <hip/hip_runtime.h>
#include <cstdint>
#include <cstddef>

#define NNODE 118
#define TSEQ  2048
#define TC    512          // chunk length
#define NCH   4
#define NEGC  -1000000000.0f

typedef __fp16 h2v __attribute__((ext_vector_type(2)));
typedef short short8 __attribute__((ext_vector_type(8)));
typedef float floatx4 __attribute__((ext_vector_type(4)));

__device__ __forceinline__ float leakyf(float x){ return x >= 0.f ? x : 0.01f * x; }
__device__ __forceinline__ float frcp(float x){ return __builtin_amdgcn_rcpf(x); }
// fast nonlinearities: v_exp + v_rcp, no fp32 div sequences
__device__ __forceinline__ float sigm(float x){ return frcp(1.f + __expf(-x)); }
__device__ __forceinline__ float tanhfast(float x){ return 1.f - 2.f * frcp(__expf(2.f * x) + 1.f); }

__device__ __forceinline__ unsigned short bf16rne(float x){
  unsigned int u = __builtin_bit_cast(unsigned int, x);
  u = (u + 0x7fffu + ((u >> 16) & 1u)) >> 16;
  return (unsigned short)u;
}

__device__ __forceinline__ float fdot2(h2v a, h2v b, float c){
#if __has_builtin(__builtin_amdgcn_fdot2)
  return __builtin_amdgcn_fdot2(a, b, c, false);
#else
  return c + (float)a.x * (float)b.x + (float)a.y * (float)b.y;
#endif
}
__device__ __forceinline__ h2v bch2(unsigned int u){ return __builtin_bit_cast(h2v, u); }

__device__ float bred_sum(float v, float* buf, int nthr){
  int tid = threadIdx.x;
  buf[tid] = v; __syncthreads();
  for (int s = nthr >> 1; s > 0; s >>= 1){
    if (tid < s) buf[tid] += buf[tid + s];
    __syncthreads();
  }
  float r = buf[0]; __syncthreads(); return r;
}
__device__ float bred_max(float v, float* buf, int nthr){
  int tid = threadIdx.x;
  buf[tid] = v; __syncthreads();
  for (int s = nthr >> 1; s > 0; s >>= 1){
    if (tid < s) buf[tid] = fmaxf(buf[tid], buf[tid + s]);
    __syncthreads();
  }
  float r = buf[0]; __syncthreads(); return r;
}

// ---------------- converts ----------------
__global__ void f32_to_bf16_k(const float* __restrict__ in, unsigned short* __restrict__ out, int n){
  int i = blockIdx.x * blockDim.x + threadIdx.x;
  if (i < n) out[i] = bf16rne(in[i]);
}
__global__ void f32_to_f16_k(const float* __restrict__ in, __fp16* __restrict__ out, int n){
  int i = blockIdx.x * blockDim.x + threadIdx.x;
  if (i < n) out[i] = (__fp16)in[i];
}

// ---------------- pre-gate GEMM (layer 1 input proj): pre[m,g] = sum_k A[m,k] W[g,k] ----------------
__global__ __launch_bounds__(256, 4) void pregemm(
    const float* __restrict__ A,             // f32 [NNODE][TSEQ][128]
    const unsigned short* __restrict__ Wb,   // bf16 [512][128]
    __fp16* __restrict__ pre,                // [NNODE*TC][512]
    int t0)
{
  const int tid = threadIdx.x, lane = tid & 63, wv = tid >> 6;
  const int blk = blockIdx.x;
  const int n = blk / (TC / 64), tb = blk % (TC / 64);
  const int rbase_pre = n * TC + tb * 64 + wv * 16;
  const size_t rbase_gl = (size_t)n * TSEQ + t0 + tb * 64 + wv * 16;
  const int r16 = lane & 15, kq = lane >> 4;
  __shared__ __fp16 lds[4][16 * 132];

  short8 af[4];
  #pragma unroll
  for (int kt = 0; kt < 4; kt++){
    const float* p = A + (rbase_gl + r16) * 128 + kt * 32 + kq * 8;
    float4 x0 = ((const float4*)p)[0];
    float4 x1 = ((const float4*)p)[1];
    short8 s;
    s[0] = (short)bf16rne(x0.x); s[1] = (short)bf16rne(x0.y);
    s[2] = (short)bf16rne(x0.z); s[3] = (short)bf16rne(x0.w);
    s[4] = (short)bf16rne(x1.x); s[5] = (short)bf16rne(x1.y);
    s[6] = (short)bf16rne(x1.z); s[7] = (short)bf16rne(x1.w);
    af[kt] = s;
  }

  __fp16* lw = &lds[wv][0];
  for (int g8 = 0; g8 < 4; g8++){
    #pragma unroll
    for (int ntc = 0; ntc < 8; ntc++){
      int nt = g8 * 8 + ntc;
      floatx4 acc = {0.f, 0.f, 0.f, 0.f};
      #pragma unroll
      for (int kt = 0; kt < 4; kt++){
        const unsigned short* bp = Wb + (size_t)(nt * 16 + r16) * 128 + kt * 32 + kq * 8;
        short8 bfr = __builtin_bit_cast(short8, *(const uint4*)bp);
        acc = __builtin_amdgcn_mfma_f32_16x16x32_bf16(af[kt], bfr, acc, 0, 0, 0);
      }
      #pragma unroll
      for (int r = 0; r < 4; r++){
        int crow = kq * 4 + r, ccol = ntc * 16 + r16;
        lw[crow * 132 + ccol] = (__fp16)acc[r];
      }
    }
    #pragma unroll
    for (int i = 0; i < 4; i++){
      int r2 = i * 4 + kq, ch = r16;
      uint4 v = *(const uint4*)&lw[r2 * 132 + ch * 8];
      *(uint4*)(pre + ((size_t)(rbase_pre + r2)) * 512 + g8 * 128 + ch * 8) = v;
    }
  }
}

// ---------------- Fused 2-layer LSTM scan, software-pipelined ----------------
// 768 threads. G0 = waves 0-3 (256 thr): layer-1 scan, 2 gate-rows/thread (W_hh0 in 128 h2v regs).
// G1 = waves 4-11 (512 thr): layer-2 scan, 1 row/thread, concatenated 256-dot
// [W_ih1|W_hh1]. [h1;h2] (128 h2v regs). h1 handed off via LDS ring; L2 lags L1 by 2 phases.
// One __syncthreads per phase. Gates packed [j][4] (i,f,g,o) -> b128 nonlin reads.
__global__ __launch_bounds__(768, 3) void lstm_fused(
    const unsigned int* __restrict__ pre1,   // fp16-pairs [NNODE][TC][256]
    const __fp16* __restrict__ Wih1,         // [512][128]
    const __fp16* __restrict__ Whh0,         // [512][128]
    const __fp16* __restrict__ Whh1,         // [512][128]
    const float* __restrict__ b_ih0, const float* __restrict__ b_hh0,
    const float* __restrict__ b_ih1, const float* __restrict__ b_hh1,
    unsigned int* __restrict__ hstate1, float* __restrict__ c1state,   // [NNODE][64] / [NNODE][128]
    unsigned int* __restrict__ hstate2, float* __restrict__ c2state,
    float* __restrict__ pout,                // [NNODE][128] or null
    int t0)
{
  const int n = blockIdx.x, tid = threadIdx.x;
  const int lane = tid & 63;
  __shared__ unsigned int hand[2][64];          // h1 handoff ring (fp16 pairs)
  __shared__ float g1buf[2][512];               // gates1 packed [j][4]
  __shared__ float g2buf[2][512];               // gates2 packed [j][4]
  __shared__ unsigned int h1own[4][64];         // G0 per-wave h1 copies
  __shared__ unsigned int h2own[8][64];         // G1 per-wave h2 copies

  if (tid < 256){
    // ================= G0: layer-1 =================
    const int i = tid, w = tid >> 6;
    h2v whA[64], whB[64];
    {
      const uint4* wa = (const uint4*)(Whh0 + (size_t)(2 * i) * 128);
      const uint4* wb = (const uint4*)(Whh0 + (size_t)(2 * i + 1) * 128);
      #pragma unroll
      for (int kk = 0; kk < 16; kk++){
        uint4 v = wa[kk];
        whA[4 * kk + 0] = bch2(v.x); whA[4 * kk + 1] = bch2(v.y);
        whA[4 * kk + 2] = bch2(v.z); whA[4 * kk + 3] = bch2(v.w);
      }
      #pragma unroll
      for (int kk = 0; kk < 16; kk++){
        uint4 v = wb[kk];
        whB[4 * kk + 0] = bch2(v.x); whB[4 * kk + 1] = bch2(v.y);
        whB[4 * kk + 2] = bch2(v.z); whB[4 * kk + 3] = bch2(v.w);
      }
    }
    const float biasA = b_ih0[2 * i] + b_hh0[2 * i];
    const float biasB = b_ih0[2 * i + 1] + b_hh0[2 * i + 1];
    const int adrA = ((2 * i) & 127) * 4 + ((2 * i) >> 7);
    const int adrB = ((2 * i + 1) & 127) * 4 + ((2 * i + 1) >> 7);

    float2 c1; unsigned int hcur1;
    if (t0 == 0){ c1.x = 0.f; c1.y = 0.f; hcur1 = 0u; }
    else { c1 = ((const float2*)c1state)[n * 64 + lane]; hcur1 = hstate1[n * 64 + lane]; }
    h1own[w][lane] = hcur1;

    const unsigned int* prow = pre1 + (size_t)n * TC * 256;
    unsigned int pv = prow[i];   // pre1[step 0]
    __syncthreads();

    #pragma unroll 1
    for (int p = 0; p < TC + 3; p++){
      // (a) nonlin1: gates1(p-1) -> h1(p-1)
      if (p >= 1 && p <= TC){
        const int rb = (p - 1) & 1;
        float4 g0 = *(const float4*)&g1buf[rb][(2 * lane) * 4];
        float4 g1 = *(const float4*)&g1buf[rb][(2 * lane + 1) * 4];
        c1.x = sigm(g0.y) * c1.x + sigm(g0.x) * tanhfast(g0.z);
        c1.y = sigm(g1.y) * c1.y + sigm(g1.x) * tanhfast(g1.z);
        float h0 = sigm(g0.w) * tanhfast(c1.x);
        float h1v = sigm(g1.w) * tanhfast(c1.y);
        h2v hp; hp.x = (__fp16)h0; hp.y = (__fp16)h1v;
        hcur1 = __builtin_bit_cast(unsigned int, hp);
        h1own[w][lane] = hcur1;
        if (w == 0) hand[(p - 1) & 1][lane] = hcur1;
      }
      // (b) GEMV1: gates1(p) from h1(p-1)
      if (p <= TC - 1){
        unsigned int pvn = 0;
        if (p + 1 <= TC - 1) pvn = prow[(size_t)(p + 1) * 256 + i];
        h2v pp = bch2(pv);
        float aA0 = (float)pp.x + biasA, aA1 = 0.f;
        float aB0 = (float)pp.y + biasB, aB1 = 0.f;
        const uint4* h4 = (const uint4*)(&h1own[w][0]);
        #pragma unroll
        for (int k = 0; k < 16; k++){
          uint4 hv = h4[k];
          h2v p0 = bch2(hv.x), p1 = bch2(hv.y), p2 = bch2(hv.z), p3 = bch2(hv.w);
          aA0 = fdot2(whA[4 * k + 0], p0, aA0);
          aA1 = fdot2(whA[4 * k + 1], p1, aA1);
          aA0 = fdot2(whA[4 * k + 2], p2, aA0);
          aA1 = fdot2(whA[4 * k + 3], p3, aA1);
          aB0 = fdot2(whB[4 * k + 0], p0, aB0);
          aB1 = fdot2(whB[4 * k + 1], p1, aB1);
          aB0 = fdot2(whB[4 * k + 2], p2, aB0);
          aB1 = fdot2(whB[4 * k + 3], p3, aB1);
        }
        g1buf[p & 1][adrA] = aA0 + aA1;
        g1buf[p & 1][adrB] = aB0 + aB1;
        pv = pvn;
      }
      __syncthreads();
    }
    if (w == 0){
      hstate1[n * 64 + lane] = hcur1;
      ((float2*)c1state)[n * 64 + lane] = c1;
    }
  } else {
    // ================= G1: layer-2 =================
    const int q = tid - 256;            // row 0..511
    const int w2 = q >> 6;              // 0..7
    h2v w1r[64], w2r[64];
    {
      const uint4* wa = (const uint4*)(Wih1 + (size_t)q * 128);
      const uint4* wb = (const uint4*)(Whh1 + (size_t)q * 128);
      #pragma unroll
      for (int kk = 0; kk < 16; kk++){
        uint4 v = wa[kk];
        w1r[4 * kk + 0] = bch2(v.x); w1r[4 * kk + 1] = bch2(v.y);
        w1r[4 * kk + 2] = bch2(v.z); w1r[4 * kk + 3] = bch2(v.w);
      }
      #pragma unroll
      for (int kk = 0; kk < 16; kk++){
        uint4 v = wb[kk];
        w2r[4 * kk + 0] = bch2(v.x); w2r[4 * kk + 1] = bch2(v.y);
        w2r[4 * kk + 2] = bch2(v.z); w2r[4 * kk + 3] = bch2(v.w);
      }
    }
    const float bias2 = b_ih1[q] + b_hh1[q];
    const int adrQ = (q & 127) * 4 + (q >> 7);

    float2 c2; unsigned int hcur2;
    if (t0 == 0){ c2.x = 0.f; c2.y = 0.f; hcur2 = 0u; }
    else { c2 = ((const float2*)c2state)[n * 64 + lane]; hcur2 = hstate2[n * 64 + lane]; }
    h2own[w2][lane] = hcur2;
    __syncthreads();

    #pragma unroll 1
    for (int p = 0; p < TC + 3; p++){
      // (a) nonlin2: gates2(p-3) -> h2(p-3)
      if (p >= 3){
        const int rb = (p - 1) & 1;
        float4 g0 = *(const float4*)&g2buf[rb][(2 * lane) * 4];
        float4 g1 = *(const float4*)&g2buf[rb][(2 * lane + 1) * 4];
        c2.x = sigm(g0.y) * c2.x + sigm(g0.x) * tanhfast(g0.z);
        c2.y = sigm(g1.y) * c2.y + sigm(g1.x) * tanhfast(g1.z);
        float h0 = sigm(g0.w) * tanhfast(c2.x);
        float h1v = sigm(g1.w) * tanhfast(c2.y);
        h2v hp; hp.x = (__fp16)h0; hp.y = (__fp16)h1v;
        hcur2 = __builtin_bit_cast(unsigned int, hp);
        h2own[w2][lane] = hcur2;
      }
      // (b) GEMV2: gates2(p-2) = [Wih1|Whh1].[h1(p-2); h2(p-3)] + bias
      if (p >= 2 && p <= TC + 1){
        float a0 = bias2, a1 = 0.f, a2 = 0.f, a3 = 0.f;
        const uint4* hh1 = (const uint4*)(&hand[p & 1][0]);   // h1(p-2)
        #pragma unroll
        for (int k = 0; k < 16; k++){
          uint4 hv = hh1[k];
          a0 = fdot2(w1r[4 * k + 0], bch2(hv.x), a0);
          a1 = fdot2(w1r[4 * k + 1], bch2(hv.y), a1);
          a2 = fdot2(w1r[4 * k + 2], bch2(hv.z), a2);
          a3 = fdot2(w1r[4 * k + 3], bch2(hv.w), a3);
        }
        const uint4* hh2 = (const uint4*)(&h2own[w2][0]);     // h2(p-3)
        #pragma unroll
        for (int k = 0; k < 16; k++){
          uint4 hv = hh2[k];
          a0 = fdot2(w2r[4 * k + 0], bch2(hv.x), a0);
          a1 = fdot2(w2r[4 * k + 1], bch2(hv.y), a1);
          a2 = fdot2(w2r[4 * k + 2], bch2(hv.z), a2);
          a3 = fdot2(w2r[4 * k + 3], bch2(hv.w), a3);
        }
        g2buf[p & 1][adrQ] = (a0 + a1) + (a2 + a3);
      }
      __syncthreads();
    }
    if (w2 == 0){
      hstate2[n * 64 + lane] = hcur2;
      ((float2*)c2state)[n * 64 + lane] = c2;
      if (pout){
        h2v hp = bch2(hcur2);
        float2 pv2; pv2.x = leakyf((float)hp.x); pv2.y = leakyf((float)hp.y);
        ((float2*)pout)[n * 64 + lane] = pv2;
      }
    }
  }
}

// ---------------- H1: per-node MLP up to n ----------------
__global__ void node_mlp(
    const float* __restrict__ x_tag, const float* __restrict__ pm,
    const float* __restrict__ Wvm, const float* __restrict__ Wup,
    const float* __restrict__ W_hyb, const float* __restrict__ b_hyb,
    const float* __restrict__ W_act, const float* __restrict__ b_act,
    const float* __restrict__ W_inact, const float* __restrict__ b_inact,
    const float* __restrict__ p, float* __restrict__ nmat)
{
  int n = blockIdx.x, tid = threadIdx.x;
  __shared__ float pl[128], up[128], vm[128], hh[256];
  float act = x_tag[n * 3 + 2], hp0 = x_tag[n * 3 + 0], hp1 = x_tag[n * 3 + 1];
  if (tid < 128) pl[tid] = p[n * 128 + tid];
  __syncthreads();
  if (tid < 128){
    float a1 = 0.f;
    for (int k = 0; k < 768; k++) a1 += pm[k] * Wvm[k * 128 + tid];
    a1 += act * Wvm[768 * 128 + tid];
    vm[tid] = leakyf(a1);
    float a2 = 0.f;
    for (int k = 0; k < 128; k++) a2 += pl[k] * Wup[k * 128 + tid];
    up[tid] = leakyf(a2);
  }
  __syncthreads();
  {
    float a = b_hyb[tid];
    for (int k = 0; k < 128; k++) a += up[k] * W_hyb[k * 256 + tid];
    for (int k = 0; k < 128; k++) a += (up[k] + vm[k]) * W_hyb[(128 + k) * 256 + tid];
    for (int k = 0; k < 128; k++) a += vm[k] * W_hyb[(256 + k) * 256 + tid];
    hh[tid] = leakyf(a);
  }
  __syncthreads();
  {
    float na = b_act[tid];
    for (int k = 0; k < 256; k++) na += hh[k] * W_act[k * 256 + tid];
    na += hp0 * W_act[256 * 256 + tid] + hp1 * W_act[257 * 256 + tid];
    float ni = b_inact[tid];
    for (int k = 0; k < 256; k++) ni += hh[k] * W_inact[k * 256 + tid];
    nmat[n * 256 + tid] = leakyf(na * (1.f - act) + ni * act);
  }
}

// ---------------- H2: per-node projections of n ----------------
__global__ void node_proj(
    const float* __restrict__ nmat,
    const float* __restrict__ Wphin, const float* __restrict__ Won,
    const float* __restrict__ Weo,
    float* __restrict__ A, float* __restrict__ B,
    float* __restrict__ C, float* __restrict__ D,
    float* __restrict__ Q, float* __restrict__ R)
{
  int n = blockIdx.x, tid = threadIdx.x;
  __shared__ float nl[256];
  nl[tid] = nmat[n * 256 + tid];
  __syncthreads();
  if (tid < 192){
    float a = 0.f, b = 0.f;
    for (int k = 0; k < 256; k++){ float v = nl[k]; a += v * Wphin[k * 192 + tid]; b += v * Wphin[(256 + k) * 192 + tid]; }
    A[n * 192 + tid] = a; B[n * 192 + tid] = b;
  }
  float c = 0.f, d = 0.f, q = 0.f, r = 0.f;
  for (int k = 0; k < 256; k++){
    float v = nl[k];
    c += v * Won[k * 256 + tid];
    d += v * Won[(256 + k) * 256 + tid];
    q += v * Weo[(256 + k) * 256 + tid];
    r += v * Weo[(512 + k) * 256 + tid];
  }
  C[n * 256 + tid] = c; D[n * 256 + tid] = d;
  Q[n * 256 + tid] = q; R[n * 256 + tid] = r;
}

// ---------------- H3: phi ----------------
__global__ void phi_kernel(const float* __restrict__ A, const float* __restrict__ B,
                           const float* __restrict__ aphi, float* __restrict__ phiT)
{
  int j = blockIdx.x, tid = threadIdx.x;
  __shared__ float Aj[192], ap[192];
  for (int k = tid; k < 192; k += 128){ Aj[k] = A[j * 192 + k]; ap[k] = aphi[k]; }
  __syncthreads();
  if (tid < NNODE){
    const float* Bi = B + (size_t)tid * 192;
    float s = 0.f;
    for (int k = 0; k < 192; k++) s += leakyf(Aj[k] + Bi[k]) * ap[k];
    phiT[j * NNODE + tid] = s;
  }
}

// ---------------- H4: masked softmaxes ----------------
__global__ void alpha_kernel(const float* __restrict__ phiT, const float* __restrict__ x_tag,
                             float* __restrict__ alpha)
{
  int j = blockIdx.x, tid = threadIdx.x;
  __shared__ float buf[128];
  bool valid = tid < NNODE;
  float ph = valid ? phiT[j * NNODE + tid] : 0.f;
  float a  = valid ? x_tag[tid * 3 + 2] : -1.f;
  bool v1 = (a == 0.f), v0 = (a == 1.f);

  float c1 = bred_sum((valid && v1) ? 1.f : 0.f, buf, 128);

  float x1 = (valid && v1) ? ph : NEGC;
  float m1 = bred_max(valid ? x1 : -3.4e38f, buf, 128);
  float e1 = valid ? __expf(x1 - m1) : 0.f;
  float s1 = bred_sum(e1, buf, 128);
  float p1 = e1 / s1;

  float x0 = (valid && v0) ? ph : NEGC;
  float m0 = bred_max(valid ? x0 : -3.4e38f, buf, 128);
  float e0 = valid ? __expf(x0 - m0) : 0.f;
  float s0 = bred_sum(e0, buf, 128);
  float p0 = e0 / s0;

  float ma = bred_max(valid ? ph : -3.4e38f, buf, 128);
  float ea = valid ? __expf(ph - ma) : 0.f;
  float sa = bred_sum(ea, buf, 128);
  float pa = ea / sa;

  float pmask = v1 ? p1 : (v0 ? p0 : ph);
  float al = (c1 > 0.f) ? pmask : pa;
  if (valid) alpha[tid * NNODE + j] = al;
}

// ---------------- H5: alpha-weighted sums ----------------
__global__ void att_sum(const float* __restrict__ alpha, const float* __restrict__ C,
                        const float* __restrict__ D, const float* __restrict__ Q,
                        const float* __restrict__ R, const float* __restrict__ nmat,
                        float* __restrict__ T1, float* __restrict__ Spart,
                        float* __restrict__ nrm)
{
  int i = blockIdx.x, tid = threadIdx.x;
  __shared__ float al[128];
  __shared__ float rb[256];
  if (tid < 128) al[tid] = (tid < NNODE) ? alpha[i * NNODE + tid] : 0.f;
  __syncthreads();
  float Di = D[i * 256 + tid];
  float acc1 = 0.f, acc2 = 0.f, sa = 0.f;
  for (int jj = 0; jj < NNODE; jj++){
    float av = al[jj]; sa += av;
    acc1 += av * leakyf(C[jj * 256 + tid] + Di);
    acc2 += av * Q[jj * 256 + tid];
  }
  T1[i * 256 + tid] = acc1;
  Spart[i * 256 + tid] = acc2 + sa * R[i * 256 + tid];
  float nv = nmat[i * 256 + tid];
  float ss = bred_sum(nv * nv, rb, 256);
  if (tid == 0) nrm[i] = fmaxf(sqrtf(ss), 1e-8f);
}

// ---------------- H6: per-node finalize ----------------
__global__ void finalize_node(const float* __restrict__ T1, const float* __restrict__ Spart,
                              const float* __restrict__ Weo, const float* __restrict__ nmat,
                              const float* __restrict__ x_tag, const float* __restrict__ Wi,
                              const float* __restrict__ bi, const float* __restrict__ nrm,
                              float* __restrict__ vvec, float* __restrict__ out)
{
  int i = blockIdx.x, tid = threadIdx.x;
  __shared__ float t1[256];
  __shared__ float rb[256];
  t1[tid] = T1[i * 256 + tid];
  __syncthreads();
  float s = Spart[i * 256 + tid];
  for (int k = 0; k < 256; k++) s += t1[k] * Weo[k * 256 + tid];
  float act = x_tag[i * 3 + 2], hp0 = x_tag[i * 3 + 0], hp1 = x_tag[i * 3 + 1];
  float hm0 = leakyf(act * s);
  float hm1 = leakyf((1.f - act) * s);
  float nd = nmat[i * 256 + tid];
  const float* Wir = Wi + (size_t)i * 1536;
  float y0 = nd * Wir[tid * 2]     + hm0 * Wir[(256 + tid) * 2]     + hm1 * Wir[(512 + tid) * 2];
  float y1 = nd * Wir[tid * 2 + 1] + hm0 * Wir[(256 + tid) * 2 + 1] + hm1 * Wir[(512 + tid) * 2 + 1];
  y0 = bred_sum(y0, rb, 256);
  y1 = bred_sum(y1, rb, 256);
  float sgn = (hp1 > hp0) ? 1.f : ((hp1 < hp0) ? -1.f : 0.f);
  if (act == 0.f && sgn != 0.f) atomicAdd(vvec + tid, sgn * nd / nrm[i]);
  if (tid == 0){
    y0 += bi[i * 2]; y1 += bi[i * 2 + 1];
    float m = fmaxf(y0, y1);
    float ee0 = __expf(y0 - m), ee1 = __expf(y1 - m);
    float ssum = ee0 + ee1;
    out[i * 2]     = ee0 / ssum;
    out[i * 2 + 1] = ee1 / ssum;
    out[236 + i * 2]     = hp0;
    out[236 + i * 2 + 1] = hp1;
    out[474 + i] = (act == 0.f) ? 1.f : 0.f;
    out[592 + i] = (act == 1.f) ? 1.f : 0.f;
  }
}

// ---------------- H_ort ----------------
__global__ void ort_kernel(const float* __restrict__ Wum, const float* __restrict__ Wvm,
                           const float* __restrict__ Wup, const float* __restrict__ Wvp,
                           float* __restrict__ misc)
{
  int a = blockIdx.x, b = threadIdx.x;
  float g1 = 0.f, g2 = 0.f, g3 = 0.f, g4 = 0.f;
  for (int r = 0; r < 769; r++){
    g1 += Wum[r * 128 + a] * Wum[r * 128 + b];
    g2 += Wvm[r * 128 + a] * Wvm[r * 128 + b];
  }
  for (int r = 0; r < 128; r++){
    g3 += Wup[r * 128 + a] * Wup[r * 128 + b];
    g4 += Wvp[r * 128 + a] * Wvp[r * 128 + b];
  }
  __shared__ float rb[128];
  float s1 = bred_sum(g1 * g2, rb, 128);
  float s2 = bred_sum(g3 * g4, rb, 128);
  if (b == 0){ atomicAdd(misc + 0, s1); atomicAdd(misc + 1, s2); }
}

// ---------------- H7: scalars ----------------
__global__ void finalize_scalars(const float* __restrict__ misc, const float* __restrict__ vvec,
                                 float* __restrict__ out)
{
  __shared__ float rb[256];
  int tid = threadIdx.x;
  float v = vvec[tid];
  float ss = bred_sum(v * v, rb, 256);
  if (tid == 0){
    out[472] = sqrtf(misc[0]) + sqrtf(misc[1]);
    out[473] = ss;
  }
}

extern "C" void kernel_launch(void* const* d_in, const int* in_sizes, int n_in,
                              void* d_out, int out_size, void* d_ws, size_t ws_size,
                              hipStream_t stream)
{
  const float* x        = (const float*)d_in[0];
  const float* x_tag    = (const float*)d_in[1];
  const float* W_ih0    = (const float*)d_in[2];
  const float* W_hh0    = (const float*)d_in[3];
  const float* b_ih0    = (const float*)d_in[4];
  const float* b_hh0    = (const float*)d_in[5];
  const float* W_ih1    = (const float*)d_in[6];
  const float* W_hh1    = (const float*)d_in[7];
  const float* b_ih1    = (const float*)d_in[8];
  const float* b_hh1    = (const float*)d_in[9];
  const float* pm       = (const float*)d_in[10];
  const float* Wum      = (const float*)d_in[11];
  const float* Wvm      = (const float*)d_in[12];
  const float* Wup      = (const float*)d_in[13];
  const float* Wvp      = (const float*)d_in[14];
  const float* W_hyb    = (const float*)d_in[15];
  const float* b_hyb    = (const float*)d_in[16];
  const float* W_act    = (const float*)d_in[17];
  const float* b_act    = (const float*)d_in[18];
  const float* W_inact  = (const float*)d_in[19];
  const float* b_inact  = (const float*)d_in[20];
  const float* Wphin    = (const float*)d_in[21];
  const float* aphi     = (const float*)d_in[22];
  const float* Won      = (const float*)d_in[23];
  const float* Weo      = (const float*)d_in[24];
  const float* Wi       = (const float*)d_in[25];
  const float* bi       = (const float*)d_in[26];
  float* out = (float*)d_out;

  char* base = (char*)d_ws;
  size_t off = 0;
  auto take = [&](size_t bytes) -> char* {
    char* p = base + off;
    off += (bytes + 255) & ~(size_t)255;
    return p;
  };
  __fp16* pre          = (__fp16*)take((size_t)NNODE * TC * 512 * 2);     // ~62MB
  unsigned short* wf0  = (unsigned short*)take((size_t)512 * 128 * 2);    // W_ih0 bf16 (MFMA)
  __fp16* wih1h        = (__fp16*)take((size_t)512 * 128 * 2);
  __fp16* whh0h        = (__fp16*)take((size_t)512 * 128 * 2);
  __fp16* whh1h        = (__fp16*)take((size_t)512 * 128 * 2);
  unsigned int* hs1    = (unsigned int*)take((size_t)NNODE * 64 * 4);
  float* c1s           = (float*)take((size_t)NNODE * 128 * 4);
  unsigned int* hs2    = (unsigned int*)take((size_t)NNODE * 64 * 4);
  float* c2s           = (float*)take((size_t)NNODE * 128 * 4);
  float* pbuf  = (float*)take((size_t)NNODE * 128 * 4);
  float* nmat  = (float*)take((size_t)NNODE * 256 * 4);
  float* Amat  = (float*)take((size_t)NNODE * 192 * 4);
  float* Bmat  = (float*)take((size_t)NNODE * 192 * 4);
  float* Cmat  = (float*)take((size_t)NNODE * 256 * 4);
  float* Dmat  = (float*)take((size_t)NNODE * 256 * 4);
  float* Qmat  = (float*)take((size_t)NNODE * 256 * 4);
  float* Rmat  = (float*)take((size_t)NNODE * 256 * 4);
  float* phiT  = (float*)take((size_t)NNODE * NNODE * 4);
  float* alpha = (float*)take((size_t)NNODE * NNODE * 4);
  float* T1    = (float*)take((size_t)NNODE * 256 * 4);
  float* Spart = (float*)take((size_t)NNODE * 256 * 4);
  float* nrm   = (float*)take((size_t)NNODE * 4);
  float* vvec  = (float*)take(256 * 4);
  float* misc  = (float*)take(8 * 4);

  hipMemsetAsync(vvec, 0, 1024 + 32, stream);

  f32_to_bf16_k<<<256, 256, 0, stream>>>(W_ih0, wf0, 512 * 128);
  f32_to_f16_k<<<256, 256, 0, stream>>>(W_ih1, wih1h, 512 * 128);
  f32_to_f16_k<<<256, 256, 0, stream>>>(W_hh0, whh0h, 512 * 128);
  f32_to_f16_k<<<256, 256, 0, stream>>>(W_hh1, whh1h, 512 * 128);

  const int gemm_grid = NNODE * (TC / 64);
  for (int c = 0; c < NCH; c++){
    pregemm<<<gemm_grid, 256, 0, stream>>>(x, wf0, pre, c * TC);
    lstm_fused<<<NNODE, 768, 0, stream>>>((const unsigned int*)pre, wih1h, whh0h, whh1h,
                                          b_ih0, b_hh0, b_ih1, b_hh1,
                                          hs1, c1s, hs2, c2s,
                                          (c == NCH - 1) ? pbuf : nullptr, c * TC);
  }

  node_mlp<<<NNODE, 256, 0, stream>>>(x_tag, pm, Wvm, Wup, W_hyb, b_hyb,
                                      W_act, b_act, W_inact, b_inact, pbuf, nmat);
  node_proj<<<NNODE, 256, 0, stream>>>(nmat, Wphin, Won, Weo, Amat, Bmat, Cmat, Dmat, Qmat, Rmat);
  phi_kernel<<<NNODE, 128, 0, stream>>>(Amat, Bmat, aphi, phiT);
  alpha_kernel<<<NNODE, 128, 0, stream>>>(phiT, x_tag, alpha);
  att_sum<<<NNODE, 256, 0, stream>>>(alpha, Cmat, Dmat, Qmat, Rmat, nmat, T1, Spart, nrm);
  finalize_node<<<NNODE, 256, 0, stream>>>(T1, Spart, Weo, nmat, x_tag, Wi, bi, nrm, vvec, out);
  ort_kernel<<<128, 128, 0, stream>>>(Wum, Wvm, Wup, Wvp, misc);
  finalize_scalars<<<1, 256, 0, stream>>>(misc, vvec, out);
}

// Round 6
// 3689.747 us; speedup vs baseline: 1.6292x; 1.0286x over previous
//
#include <hip/hip_runtime.h>
#include <cstdint>
#include <cstddef>

#define NNODE 118
#define TSEQ  2048
#define TC    512          // chunk length
#define NCH   4
#define NEGC  -1000000000.0f

typedef __fp16 h2v __attribute__((ext_vector_type(2)));
typedef short short8 __attribute__((ext_vector_type(8)));
typedef float floatx4 __attribute__((ext_vector_type(4)));

__device__ __forceinline__ float leakyf(float x){ return x >= 0.f ? x : 0.01f * x; }
__device__ __forceinline__ float frcp(float x){ return __builtin_amdgcn_rcpf(x); }
__device__ __forceinline__ float sigm(float x){ return frcp(1.f + __expf(-x)); }
__device__ __forceinline__ float tanhfast(float x){ return 1.f - 2.f * frcp(__expf(2.f * x) + 1.f); }

__device__ __forceinline__ unsigned short bf16rne(float x){
  unsigned int u = __builtin_bit_cast(unsigned int, x);
  u = (u + 0x7fffu + ((u >> 16) & 1u)) >> 16;
  return (unsigned short)u;
}

__device__ __forceinline__ float fdot2(h2v a, h2v b, float c){
#if __has_builtin(__builtin_amdgcn_fdot2)
  return __builtin_amdgcn_fdot2(a, b, c, false);
#else
  return c + (float)a.x * (float)b.x + (float)a.y * (float)b.y;
#endif
}
__device__ __forceinline__ h2v bch2(unsigned int u){ return __builtin_bit_cast(h2v, u); }

__device__ float bred_sum(float v, float* buf, int nthr){
  int tid = threadIdx.x;
  buf[tid] = v; __syncthreads();
  for (int s = nthr >> 1; s > 0; s >>= 1){
    if (tid < s) buf[tid] += buf[tid + s];
    __syncthreads();
  }
  float r = buf[0]; __syncthreads(); return r;
}
__device__ float bred_max(float v, float* buf, int nthr){
  int tid = threadIdx.x;
  buf[tid] = v; __syncthreads();
  for (int s = nthr >> 1; s > 0; s >>= 1){
    if (tid < s) buf[tid] = fmaxf(buf[tid], buf[tid + s]);
    __syncthreads();
  }
  float r = buf[0]; __syncthreads(); return r;
}

// ---------------- converts ----------------
__global__ void f32_to_bf16_k(const float* __restrict__ in, unsigned short* __restrict__ out, int n){
  int i = blockIdx.x * blockDim.x + threadIdx.x;
  if (i < n) out[i] = bf16rne(in[i]);
}
__global__ void f32_to_f16_k(const float* __restrict__ in, __fp16* __restrict__ out, int n){
  int i = blockIdx.x * blockDim.x + threadIdx.x;
  if (i < n) out[i] = (__fp16)in[i];
}

// ---------------- pre-gate GEMM (layer 1 input proj) ----------------
__global__ __launch_bounds__(256, 4) void pregemm(
    const float* __restrict__ A,             // f32 [NNODE][TSEQ][128]
    const unsigned short* __restrict__ Wb,   // bf16 [512][128]
    __fp16* __restrict__ pre,                // [NNODE*TC][512]
    int t0)
{
  const int tid = threadIdx.x, lane = tid & 63, wv = tid >> 6;
  const int blk = blockIdx.x;
  const int n = blk / (TC / 64), tb = blk % (TC / 64);
  const int rbase_pre = n * TC + tb * 64 + wv * 16;
  const size_t rbase_gl = (size_t)n * TSEQ + t0 + tb * 64 + wv * 16;
  const int r16 = lane & 15, kq = lane >> 4;
  __shared__ __fp16 lds[4][16 * 132];

  short8 af[4];
  #pragma unroll
  for (int kt = 0; kt < 4; kt++){
    const float* p = A + (rbase_gl + r16) * 128 + kt * 32 + kq * 8;
    float4 x0 = ((const float4*)p)[0];
    float4 x1 = ((const float4*)p)[1];
    short8 s;
    s[0] = (short)bf16rne(x0.x); s[1] = (short)bf16rne(x0.y);
    s[2] = (short)bf16rne(x0.z); s[3] = (short)bf16rne(x0.w);
    s[4] = (short)bf16rne(x1.x); s[5] = (short)bf16rne(x1.y);
    s[6] = (short)bf16rne(x1.z); s[7] = (short)bf16rne(x1.w);
    af[kt] = s;
  }

  __fp16* lw = &lds[wv][0];
  for (int g8 = 0; g8 < 4; g8++){
    #pragma unroll
    for (int ntc = 0; ntc < 8; ntc++){
      int nt = g8 * 8 + ntc;
      floatx4 acc = {0.f, 0.f, 0.f, 0.f};
      #pragma unroll
      for (int kt = 0; kt < 4; kt++){
        const unsigned short* bp = Wb + (size_t)(nt * 16 + r16) * 128 + kt * 32 + kq * 8;
        short8 bfr = __builtin_bit_cast(short8, *(const uint4*)bp);
        acc = __builtin_amdgcn_mfma_f32_16x16x32_bf16(af[kt], bfr, acc, 0, 0, 0);
      }
      #pragma unroll
      for (int r = 0; r < 4; r++){
        int crow = kq * 4 + r, ccol = ntc * 16 + r16;
        lw[crow * 132 + ccol] = (__fp16)acc[r];
      }
    }
    #pragma unroll
    for (int i = 0; i < 4; i++){
      int r2 = i * 4 + kq, ch = r16;
      uint4 v = *(const uint4*)&lw[r2 * 132 + ch * 8];
      *(uint4*)(pre + ((size_t)(rbase_pre + r2)) * 512 + g8 * 128 + ch * 8) = v;
    }
  }
}

// ---------------- Fused 2-layer LSTM scan, software-pipelined ----------------
// 768 threads. G0 = waves 0-3: layer-1, 2 gate-rows/thread. G1 = waves 4-11: layer-2,
// 1 row/thread, concatenated 256-dot [Wih1|Whh1].[h1;h2]. h1 handoff via LDS ring.
// v6: linear gate layout (no bank conflicts) + pre staged to LDS 16 steps at a time
// (double-buffered; barrier vmcnt-drain amortized 16x).
__global__ __launch_bounds__(768, 3) void lstm_fused(
    const unsigned int* __restrict__ pre1,   // fp16-pairs [NNODE][TC][256]
    const __fp16* __restrict__ Wih1,         // [512][128]
    const __fp16* __restrict__ Whh0,         // [512][128]
    const __fp16* __restrict__ Whh1,         // [512][128]
    const float* __restrict__ b_ih0, const float* __restrict__ b_hh0,
    const float* __restrict__ b_ih1, const float* __restrict__ b_hh1,
    unsigned int* __restrict__ hstate1, float* __restrict__ c1state,
    unsigned int* __restrict__ hstate2, float* __restrict__ c2state,
    float* __restrict__ pout,                // [NNODE][128] or null
    int t0)
{
  const int n = blockIdx.x, tid = threadIdx.x;
  const int lane = tid & 63;
  __shared__ unsigned int hand[2][64];          // h1 handoff ring
  __shared__ float g1buf[2][512];               // gates1, linear [row]
  __shared__ float g2buf[2][512];               // gates2, linear [row]
  __shared__ unsigned int h1own[4][64];         // G0 per-wave h1 copies
  __shared__ unsigned int h2own[8][64];         // G1 per-wave h2 copies
  __shared__ unsigned int lds_pre[2][16 * 256]; // staged pre-gates, 16 steps x dbuf (32KB)

  if (tid < 256){
    // ================= G0: layer-1 =================
    const int i = tid, w = tid >> 6;
    h2v whA[64], whB[64];
    {
      const uint4* wa = (const uint4*)(Whh0 + (size_t)(2 * i) * 128);
      const uint4* wb = (const uint4*)(Whh0 + (size_t)(2 * i + 1) * 128);
      #pragma unroll
      for (int kk = 0; kk < 16; kk++){
        uint4 v = wa[kk];
        whA[4 * kk + 0] = bch2(v.x); whA[4 * kk + 1] = bch2(v.y);
        whA[4 * kk + 2] = bch2(v.z); whA[4 * kk + 3] = bch2(v.w);
      }
      #pragma unroll
      for (int kk = 0; kk < 16; kk++){
        uint4 v = wb[kk];
        whB[4 * kk + 0] = bch2(v.x); whB[4 * kk + 1] = bch2(v.y);
        whB[4 * kk + 2] = bch2(v.z); whB[4 * kk + 3] = bch2(v.w);
      }
    }
    const float biasA = b_ih0[2 * i] + b_hh0[2 * i];
    const float biasB = b_ih0[2 * i + 1] + b_hh0[2 * i + 1];

    float2 c1; unsigned int hcur1;
    if (t0 == 0){ c1.x = 0.f; c1.y = 0.f; hcur1 = 0u; }
    else { c1 = ((const float2*)c1state)[n * 64 + lane]; hcur1 = hstate1[n * 64 + lane]; }
    h1own[w][lane] = hcur1;

    const uint4* prow4 = (const uint4*)(pre1 + (size_t)n * TC * 256);
    // stage batch 0 (steps 0..15) into lds_pre[0]
    {
      uint4* dst = (uint4*)&lds_pre[0][0];
      #pragma unroll
      for (int j = 0; j < 4; j++) dst[j * 256 + i] = prow4[j * 256 + i];
    }
    __syncthreads();

    #pragma unroll 1
    for (int p = 0; p < TC + 3; p++){
      // (a) nonlin1: gates1(p-1) -> h1(p-1)
      if (p >= 1 && p <= TC){
        const int rb = (p - 1) & 1;
        float2 gi = *(const float2*)&g1buf[rb][2 * lane];
        float2 gf = *(const float2*)&g1buf[rb][128 + 2 * lane];
        float2 gg = *(const float2*)&g1buf[rb][256 + 2 * lane];
        float2 go = *(const float2*)&g1buf[rb][384 + 2 * lane];
        c1.x = sigm(gf.x) * c1.x + sigm(gi.x) * tanhfast(gg.x);
        c1.y = sigm(gf.y) * c1.y + sigm(gi.y) * tanhfast(gg.y);
        float h0 = sigm(go.x) * tanhfast(c1.x);
        float h1v = sigm(go.y) * tanhfast(c1.y);
        h2v hp; hp.x = (__fp16)h0; hp.y = (__fp16)h1v;
        hcur1 = __builtin_bit_cast(unsigned int, hp);
        h1own[w][lane] = hcur1;
        if (w == 0) hand[(p - 1) & 1][lane] = hcur1;
      }
      // (b) GEMV1: gates1(p) from h1(p-1), pre from LDS stage
      if (p <= TC - 1){
        float aA0 = biasA, aA1 = 0.f;
        float aB0 = biasB, aB1 = 0.f;
        {
          h2v pp = bch2(lds_pre[(p >> 4) & 1][(p & 15) * 256 + i]);
          aA0 += (float)pp.x; aB0 += (float)pp.y;
        }
        const uint4* h4 = (const uint4*)(&h1own[w][0]);
        #pragma unroll
        for (int k = 0; k < 16; k++){
          uint4 hv = h4[k];
          h2v p0 = bch2(hv.x), p1 = bch2(hv.y), p2 = bch2(hv.z), p3 = bch2(hv.w);
          aA0 = fdot2(whA[4 * k + 0], p0, aA0);
          aA1 = fdot2(whA[4 * k + 1], p1, aA1);
          aA0 = fdot2(whA[4 * k + 2], p2, aA0);
          aA1 = fdot2(whA[4 * k + 3], p3, aA1);
          aB0 = fdot2(whB[4 * k + 0], p0, aB0);
          aB1 = fdot2(whB[4 * k + 1], p1, aB1);
          aB0 = fdot2(whB[4 * k + 2], p2, aB0);
          aB1 = fdot2(whB[4 * k + 3], p3, aB1);
        }
        float2 gw; gw.x = aA0 + aA1; gw.y = aB0 + aB1;
        *(float2*)&g1buf[p & 1][2 * i] = gw;
      }
      // (c) stage next 16-step batch (first phase of each batch; dbuf -> no race)
      if ((p & 15) == 0){
        int bnext = (p >> 4) + 1;
        if (bnext < TC / 16){
          uint4* dst = (uint4*)&lds_pre[bnext & 1][0];
          const uint4* src = prow4 + (size_t)bnext * 1024;
          #pragma unroll
          for (int j = 0; j < 4; j++) dst[j * 256 + i] = src[j * 256 + i];
        }
      }
      __syncthreads();
    }
    if (w == 0){
      hstate1[n * 64 + lane] = hcur1;
      ((float2*)c1state)[n * 64 + lane] = c1;
    }
  } else {
    // ================= G1: layer-2 =================
    const int q = tid - 256;
    const int w2 = q >> 6;
    h2v w1r[64], w2r[64];
    {
      const uint4* wa = (const uint4*)(Wih1 + (size_t)q * 128);
      const uint4* wb = (const uint4*)(Whh1 + (size_t)q * 128);
      #pragma unroll
      for (int kk = 0; kk < 16; kk++){
        uint4 v = wa[kk];
        w1r[4 * kk + 0] = bch2(v.x); w1r[4 * kk + 1] = bch2(v.y);
        w1r[4 * kk + 2] = bch2(v.z); w1r[4 * kk + 3] = bch2(v.w);
      }
      #pragma unroll
      for (int kk = 0; kk < 16; kk++){
        uint4 v = wb[kk];
        w2r[4 * kk + 0] = bch2(v.x); w2r[4 * kk + 1] = bch2(v.y);
        w2r[4 * kk + 2] = bch2(v.z); w2r[4 * kk + 3] = bch2(v.w);
      }
    }
    const float bias2 = b_ih1[q] + b_hh1[q];

    float2 c2; unsigned int hcur2;
    if (t0 == 0){ c2.x = 0.f; c2.y = 0.f; hcur2 = 0u; }
    else { c2 = ((const float2*)c2state)[n * 64 + lane]; hcur2 = hstate2[n * 64 + lane]; }
    h2own[w2][lane] = hcur2;
    __syncthreads();

    #pragma unroll 1
    for (int p = 0; p < TC + 3; p++){
      // (a) nonlin2: gates2(p-3) -> h2(p-3)
      if (p >= 3){
        const int rb = (p - 1) & 1;
        float2 gi = *(const float2*)&g2buf[rb][2 * lane];
        float2 gf = *(const float2*)&g2buf[rb][128 + 2 * lane];
        float2 gg = *(const float2*)&g2buf[rb][256 + 2 * lane];
        float2 go = *(const float2*)&g2buf[rb][384 + 2 * lane];
        c2.x = sigm(gf.x) * c2.x + sigm(gi.x) * tanhfast(gg.x);
        c2.y = sigm(gf.y) * c2.y + sigm(gi.y) * tanhfast(gg.y);
        float h0 = sigm(go.x) * tanhfast(c2.x);
        float h1v = sigm(go.y) * tanhfast(c2.y);
        h2v hp; hp.x = (__fp16)h0; hp.y = (__fp16)h1v;
        hcur2 = __builtin_bit_cast(unsigned int, hp);
        h2own[w2][lane] = hcur2;
      }
      // (b) GEMV2: gates2(p-2) = [Wih1|Whh1].[h1(p-2); h2(p-3)] + bias
      if (p >= 2 && p <= TC + 1){
        float a0 = bias2, a1 = 0.f, a2 = 0.f, a3 = 0.f;
        const uint4* hh1 = (const uint4*)(&hand[p & 1][0]);
        #pragma unroll
        for (int k = 0; k < 16; k++){
          uint4 hv = hh1[k];
          a0 = fdot2(w1r[4 * k + 0], bch2(hv.x), a0);
          a1 = fdot2(w1r[4 * k + 1], bch2(hv.y), a1);
          a2 = fdot2(w1r[4 * k + 2], bch2(hv.z), a2);
          a3 = fdot2(w1r[4 * k + 3], bch2(hv.w), a3);
        }
        const uint4* hh2 = (const uint4*)(&h2own[w2][0]);
        #pragma unroll
        for (int k = 0; k < 16; k++){
          uint4 hv = hh2[k];
          a0 = fdot2(w2r[4 * k + 0], bch2(hv.x), a0);
          a1 = fdot2(w2r[4 * k + 1], bch2(hv.y), a1);
          a2 = fdot2(w2r[4 * k + 2], bch2(hv.z), a2);
          a3 = fdot2(w2r[4 * k + 3], bch2(hv.w), a3);
        }
        g2buf[p & 1][q] = (a0 + a1) + (a2 + a3);
      }
      __syncthreads();
    }
    if (w2 == 0){
      hstate2[n * 64 + lane] = hcur2;
      ((float2*)c2state)[n * 64 + lane] = c2;
      if (pout){
        h2v hp = bch2(hcur2);
        float2 pv2; pv2.x = leakyf((float)hp.x); pv2.y = leakyf((float)hp.y);
        ((float2*)pout)[n * 64 + lane] = pv2;
      }
    }
  }
}

// ---------------- H1: per-node MLP up to n ----------------
__global__ void node_mlp(
    const float* __restrict__ x_tag, const float* __restrict__ pm,
    const float* __restrict__ Wvm, const float* __restrict__ Wup,
    const float* __restrict__ W_hyb, const float* __restrict__ b_hyb,
    const float* __restrict__ W_act, const float* __restrict__ b_act,
    const float* __restrict__ W_inact, const float* __restrict__ b_inact,
    const float* __restrict__ p, float* __restrict__ nmat)
{
  int n = blockIdx.x, tid = threadIdx.x;
  __shared__ float pl[128], up[128], vm[128], hh[256];
  float act = x_tag[n * 3 + 2], hp0 = x_tag[n * 3 + 0], hp1 = x_tag[n * 3 + 1];
  if (tid < 128) pl[tid] = p[n * 128 + tid];
  __syncthreads();
  if (tid < 128){
    float a1 = 0.f;
    for (int k = 0; k < 768; k++) a1 += pm[k] * Wvm[k * 128 + tid];
    a1 += act * Wvm[768 * 128 + tid];
    vm[tid] = leakyf(a1);
    float a2 = 0.f;
    for (int k = 0; k < 128; k++) a2 += pl[k] * Wup[k * 128 + tid];
    up[tid] = leakyf(a2);
  }
  __syncthreads();
  {
    float a = b_hyb[tid];
    for (int k = 0; k < 128; k++) a += up[k] * W_hyb[k * 256 + tid];
    for (int k = 0; k < 128; k++) a += (up[k] + vm[k]) * W_hyb[(128 + k) * 256 + tid];
    for (int k = 0; k < 128; k++) a += vm[k] * W_hyb[(256 + k) * 256 + tid];
    hh[tid] = leakyf(a);
  }
  __syncthreads();
  {
    float na = b_act[tid];
    for (int k = 0; k < 256; k++) na += hh[k] * W_act[k * 256 + tid];
    na += hp0 * W_act[256 * 256 + tid] + hp1 * W_act[257 * 256 + tid];
    float ni = b_inact[tid];
    for (int k = 0; k < 256; k++) ni += hh[k] * W_inact[k * 256 + tid];
    nmat[n * 256 + tid] = leakyf(na * (1.f - act) + ni * act);
  }
}

// ---------------- H2: per-node projections of n ----------------
__global__ void node_proj(
    const float* __restrict__ nmat,
    const float* __restrict__ Wphin, const float* __restrict__ Won,
    const float* __restrict__ Weo,
    float* __restrict__ A, float* __restrict__ B,
    float* __restrict__ C, float* __restrict__ D,
    float* __restrict__ Q, float* __restrict__ R)
{
  int n = blockIdx.x, tid = threadIdx.x;
  __shared__ float nl[256];
  nl[tid] = nmat[n * 256 + tid];
  __syncthreads();
  if (tid < 192){
    float a = 0.f, b = 0.f;
    for (int k = 0; k < 256; k++){ float v = nl[k]; a += v * Wphin[k * 192 + tid]; b += v * Wphin[(256 + k) * 192 + tid]; }
    A[n * 192 + tid] = a; B[n * 192 + tid] = b;
  }
  float c = 0.f, d = 0.f, q = 0.f, r = 0.f;
  for (int k = 0; k < 256; k++){
    float v = nl[k];
    c += v * Won[k * 256 + tid];
    d += v * Won[(256 + k) * 256 + tid];
    q += v * Weo[(256 + k) * 256 + tid];
    r += v * Weo[(512 + k) * 256 + tid];
  }
  C[n * 256 + tid] = c; D[n * 256 + tid] = d;
  Q[n * 256 + tid] = q; R[n * 256 + tid] = r;
}

// ---------------- H3: phi ----------------
__global__ void phi_kernel(const float* __restrict__ A, const float* __restrict__ B,
                           const float* __restrict__ aphi, float* __restrict__ phiT)
{
  int j = blockIdx.x, tid = threadIdx.x;
  __shared__ float Aj[192], ap[192];
  for (int k = tid; k < 192; k += 128){ Aj[k] = A[j * 192 + k]; ap[k] = aphi[k]; }
  __syncthreads();
  if (tid < NNODE){
    const float* Bi = B + (size_t)tid * 192;
    float s = 0.f;
    for (int k = 0; k < 192; k++) s += leakyf(Aj[k] + Bi[k]) * ap[k];
    phiT[j * NNODE + tid] = s;
  }
}

// ---------------- H4: masked softmaxes ----------------
__global__ void alpha_kernel(const float* __restrict__ phiT, const float* __restrict__ x_tag,
                             float* __restrict__ alpha)
{
  int j = blockIdx.x, tid = threadIdx.x;
  __shared__ float buf[128];
  bool valid = tid < NNODE;
  float ph = valid ? phiT[j * NNODE + tid] : 0.f;
  float a  = valid ? x_tag[tid * 3 + 2] : -1.f;
  bool v1 = (a == 0.f), v0 = (a == 1.f);

  float c1 = bred_sum((valid && v1) ? 1.f : 0.f, buf, 128);

  float x1 = (valid && v1) ? ph : NEGC;
  float m1 = bred_max(valid ? x1 : -3.4e38f, buf, 128);
  float e1 = valid ? __expf(x1 - m1) : 0.f;
  float s1 = bred_sum(e1, buf, 128);
  float p1 = e1 / s1;

  float x0 = (valid && v0) ? ph : NEGC;
  float m0 = bred_max(valid ? x0 : -3.4e38f, buf, 128);
  float e0 = valid ? __expf(x0 - m0) : 0.f;
  float s0 = bred_sum(e0, buf, 128);
  float p0 = e0 / s0;

  float ma = bred_max(valid ? ph : -3.4e38f, buf, 128);
  float ea = valid ? __expf(ph - ma) : 0.f;
  float sa = bred_sum(ea, buf, 128);
  float pa = ea / sa;

  float pmask = v1 ? p1 : (v0 ? p0 : ph);
  float al = (c1 > 0.f) ? pmask : pa;
  if (valid) alpha[tid * NNODE + j] = al;
}

// ---------------- H5: alpha-weighted sums ----------------
__global__ void att_sum(const float* __restrict__ alpha, const float* __restrict__ C,
                        const float* __restrict__ D, const float* __restrict__ Q,
                        const float* __restrict__ R, const float* __restrict__ nmat,
                        float* __restrict__ T1, float* __restrict__ Spart,
                        float* __restrict__ nrm)
{
  int i = blockIdx.x, tid = threadIdx.x;
  __shared__ float al[128];
  __shared__ float rb[256];
  if (tid < 128) al[tid] = (tid < NNODE) ? alpha[i * NNODE + tid] : 0.f;
  __syncthreads();
  float Di = D[i * 256 + tid];
  float acc1 = 0.f, acc2 = 0.f, sa = 0.f;
  for (int jj = 0; jj < NNODE; jj++){
    float av = al[jj]; sa += av;
    acc1 += av * leakyf(C[jj * 256 + tid] + Di);
    acc2 += av * Q[jj * 256 + tid];
  }
  T1[i * 256 + tid] = acc1;
  Spart[i * 256 + tid] = acc2 + sa * R[i * 256 + tid];
  float nv = nmat[i * 256 + tid];
  float ss = bred_sum(nv * nv, rb, 256);
  if (tid == 0) nrm[i] = fmaxf(sqrtf(ss), 1e-8f);
}

// ---------------- H6: per-node finalize ----------------
__global__ void finalize_node(const float* __restrict__ T1, const float* __restrict__ Spart,
                              const float* __restrict__ Weo, const float* __restrict__ nmat,
                              const float* __restrict__ x_tag, const float* __restrict__ Wi,
                              const float* __restrict__ bi, const float* __restrict__ nrm,
                              float* __restrict__ vvec, float* __restrict__ out)
{
  int i = blockIdx.x, tid = threadIdx.x;
  __shared__ float t1[256];
  __shared__ float rb[256];
  t1[tid] = T1[i * 256 + tid];
  __syncthreads();
  float s = Spart[i * 256 + tid];
  for (int k = 0; k < 256; k++) s += t1[k] * Weo[k * 256 + tid];
  float act = x_tag[i * 3 + 2], hp0 = x_tag[i * 3 + 0], hp1 = x_tag[i * 3 + 1];
  float hm0 = leakyf(act * s);
  float hm1 = leakyf((1.f - act) * s);
  float nd = nmat[i * 256 + tid];
  const float* Wir = Wi + (size_t)i * 1536;
  float y0 = nd * Wir[tid * 2]     + hm0 * Wir[(256 + tid) * 2]     + hm1 * Wir[(512 + tid) * 2];
  float y1 = nd * Wir[tid * 2 + 1] + hm0 * Wir[(256 + tid) * 2 + 1] + hm1 * Wir[(512 + tid) * 2 + 1];
  y0 = bred_sum(y0, rb, 256);
  y1 = bred_sum(y1, rb, 256);
  float sgn = (hp1 > hp0) ? 1.f : ((hp1 < hp0) ? -1.f : 0.f);
  if (act == 0.f && sgn != 0.f) atomicAdd(vvec + tid, sgn * nd / nrm[i]);
  if (tid == 0){
    y0 += bi[i * 2]; y1 += bi[i * 2 + 1];
    float m = fmaxf(y0, y1);
    float ee0 = __expf(y0 - m), ee1 = __expf(y1 - m);
    float ssum = ee0 + ee1;
    out[i * 2]     = ee0 / ssum;
    out[i * 2 + 1] = ee1 / ssum;
    out[236 + i * 2]     = hp0;
    out[236 + i * 2 + 1] = hp1;
    out[474 + i] = (act == 0.f) ? 1.f : 0.f;
    out[592 + i] = (act == 1.f) ? 1.f : 0.f;
  }
}

// ---------------- H_ort ----------------
__global__ void ort_kernel(const float* __restrict__ Wum, const float* __restrict__ Wvm,
                           const float* __restrict__ Wup, const float* __restrict__ Wvp,
                           float* __restrict__ misc)
{
  int a = blockIdx.x, b = threadIdx.x;
  float g1 = 0.f, g2 = 0.f, g3 = 0.f, g4 = 0.f;
  for (int r = 0; r < 769; r++){
    g1 += Wum[r * 128 + a] * Wum[r * 128 + b];
    g2 += Wvm[r * 128 + a] * Wvm[r * 128 + b];
  }
  for (int r = 0; r < 128; r++){
    g3 += Wup[r * 128 + a] * Wup[r * 128 + b];
    g4 += Wvp[r * 128 + a] * Wvp[r * 128 + b];
  }
  __shared__ float rb[128];
  float s1 = bred_sum(g1 * g2, rb, 128);
  float s2 = bred_sum(g3 * g4, rb, 128);
  if (b == 0){ atomicAdd(misc + 0, s1); atomicAdd(misc + 1, s2); }
}

// ---------------- H7: scalars ----------------
__global__ void finalize_scalars(const float* __restrict__ misc, const float* __restrict__ vvec,
                                 float* __restrict__ out)
{
  __shared__ float rb[256];
  int tid = threadIdx.x;
  float v = vvec[tid];
  float ss = bred_sum(v * v, rb, 256);
  if (tid == 0){
    out[472] = sqrtf(misc[0]) + sqrtf(misc[1]);
    out[473] = ss;
  }
}

extern "C" void kernel_launch(void* const* d_in, const int* in_sizes, int n_in,
                              void* d_out, int out_size, void* d_ws, size_t ws_size,
                              hipStream_t stream)
{
  const float* x        = (const float*)d_in[0];
  const float* x_tag    = (const float*)d_in[1];
  const float* W_ih0    = (const float*)d_in[2];
  const float* W_hh0    = (const float*)d_in[3];
  const float* b_ih0    = (const float*)d_in[4];
  const float* b_hh0    = (const float*)d_in[5];
  const float* W_ih1    = (const float*)d_in[6];
  const float* W_hh1    = (const float*)d_in[7];
  const float* b_ih1    = (const float*)d_in[8];
  const float* b_hh1    = (const float*)d_in[9];
  const float* pm       = (const float*)d_in[10];
  const float* Wum      = (const float*)d_in[11];
  const float* Wvm      = (const float*)d_in[12];
  const float* Wup      = (const float*)d_in[13];
  const float* Wvp      = (const float*)d_in[14];
  const float* W_hyb    = (const float*)d_in[15];
  const float* b_hyb    = (const float*)d_in[16];
  const float* W_act    = (const float*)d_in[17];
  const float* b_act    = (const float*)d_in[18];
  const float* W_inact  = (const float*)d_in[19];
  const float* b_inact  = (const float*)d_in[20];
  const float* Wphin    = (const float*)d_in[21];
  const float* aphi     = (const float*)d_in[22];
  const float* Won      = (const float*)d_in[23];
  const float* Weo      = (const float*)d_in[24];
  const float* Wi       = (const float*)d_in[25];
  const float* bi       = (const float*)d_in[26];
  float* out = (float*)d_out;

  char* base = (char*)d_ws;
  size_t off = 0;
  auto take = [&](size_t bytes) -> char* {
    char* p = base + off;
    off += (bytes + 255) & ~(size_t)255;
    return p;
  };
  __fp16* pre          = (__fp16*)take((size_t)NNODE * TC * 512 * 2);     // ~62MB
  unsigned short* wf0  = (unsigned short*)take((size_t)512 * 128 * 2);
  __fp16* wih1h        = (__fp16*)take((size_t)512 * 128 * 2);
  __fp16* whh0h        = (__fp16*)take((size_t)512 * 128 * 2);
  __fp16* whh1h        = (__fp16*)take((size_t)512 * 128 * 2);
  unsigned int* hs1    = (unsigned int*)take((size_t)NNODE * 64 * 4);
  float* c1s           = (float*)take((size_t)NNODE * 128 * 4);
  unsigned int* hs2    = (unsigned int*)take((size_t)NNODE * 64 * 4);
  float* c2s           = (float*)take((size_t)NNODE * 128 * 4);
  float* pbuf  = (float*)take((size_t)NNODE * 128 * 4);
  float* nmat  = (float*)take((size_t)NNODE * 256 * 4);
  float* Amat  = (float*)take((size_t)NNODE * 192 * 4);
  float* Bmat  = (float*)take((size_t)NNODE * 192 * 4);
  float* Cmat  = (float*)take((size_t)NNODE * 256 * 4);
  float* Dmat  = (float*)take((size_t)NNODE * 256 * 4);
  float* Qmat  = (float*)take((size_t)NNODE * 256 * 4);
  float* Rmat  = (float*)take((size_t)NNODE * 256 * 4);
  float* phiT  = (float*)take((size_t)NNODE * NNODE * 4);
  float* alpha = (float*)take((size_t)NNODE * NNODE * 4);
  float* T1    = (float*)take((size_t)NNODE * 256 * 4);
  float* Spart = (float*)take((size_t)NNODE * 256 * 4);
  float* nrm   = (float*)take((size_t)NNODE * 4);
  float* vvec  = (float*)take(256 * 4);
  float* misc  = (float*)take(8 * 4);

  hipMemsetAsync(vvec, 0, 1024 + 32, stream);

  f32_to_bf16_k<<<256, 256, 0, stream>>>(W_ih0, wf0, 512 * 128);
  f32_to_f16_k<<<256, 256, 0, stream>>>(W_ih1, wih1h, 512 * 128);
  f32_to_f16_k<<<256, 256, 0, stream>>>(W_hh0, whh0h, 512 * 128);
  f32_to_f16_k<<<256, 256, 0, stream>>>(W_hh1, whh1h, 512 * 128);

  const int gemm_grid = NNODE * (TC / 64);
  for (int c = 0; c < NCH; c++){
    pregemm<<<gemm_grid, 256, 0, stream>>>(x, wf0, pre, c * TC);
    lstm_fused<<<NNODE, 768, 0, stream>>>((const unsigned int*)pre, wih1h, whh0h, whh1h,
                                          b_ih0, b_hh0, b_ih1, b_hh1,
                                          hs1, c1s, hs2, c2s,
                                          (c == NCH - 1) ? pbuf : nullptr, c * TC);
  }

  node_mlp<<<NNODE, 256, 0, stream>>>(x_tag, pm, Wvm, Wup, W_hyb, b_hyb,
                                      W_act, b_act, W_inact, b_inact, pbuf, nmat);
  node_proj<<<NNODE, 256, 0, stream>>>(nmat, Wphin, Won, Weo, Amat, Bmat, Cmat, Dmat, Qmat, Rmat);
  phi_kernel<<<NNODE, 128, 0, stream>>>(Amat, Bmat, aphi, phiT);
  alpha_kernel<<<NNODE, 128, 0, stream>>>(phiT, x_tag, alpha);
  att_sum<<<NNODE, 256, 0, stream>>>(alpha, Cmat, Dmat, Qmat, Rmat, nmat, T1, Spart, nrm);
  finalize_node<<<NNODE, 256, 0, stream>>>(T1, Spart, Weo, nmat, x_tag, Wi, bi, nrm, vvec, out);
  ort_kernel<<<128, 128, 0, stream>>>(Wum, Wvm, Wup, Wvp, misc);
  finalize_scalars<<<1, 256, 0, stream>>>(misc, vvec, out);
}